// Round 1
// baseline (1835.612 us; speedup 1.0000x reference)
//
#include <hip/hip_runtime.h>
#include <math.h>

#define B_ 4096
#define T_ 64
#define V_ 512
#define E_ 32
#define H_ 128
#define G_ 384   // 3H
#define FC1_ 256
#define O_ 1024

__device__ __forceinline__ float sigf(float x) { return 1.0f / (1.0f + __expf(-x)); }
__device__ __forceinline__ float tanhfast(float x) {
    // tanh(x) = 1 - 2/(exp(2x)+1); correct limits at +-inf
    return 1.0f - 2.0f / (__expf(2.0f * x) + 1.0f);
}
__device__ __forceinline__ float eluf(float x) { return x > 0.0f ? x : (__expf(x) - 1.0f); }

// ---------------- weight transposes (tiny) ----------------
__global__ void prep_kernel(const float* __restrict__ Wih, const float* __restrict__ Whh,
                            const float* __restrict__ Wfc1, const float* __restrict__ Wfc2,
                            float* __restrict__ wihT, float* __restrict__ whhT,
                            float* __restrict__ wfc1T, float* __restrict__ wfc2T) {
    int id = blockIdx.x * blockDim.x + threadIdx.x;
    int np = gridDim.x * blockDim.x;
    for (int i = id; i < G_ * E_; i += np) {           // W_ih [384][32] -> [32][384]
        int g = i >> 5, e = i & 31;
        wihT[e * G_ + g] = Wih[i];
    }
    for (int i = id; i < G_ * H_; i += np) {           // W_hh [384][128] -> [128][384]
        int g = i >> 7, k = i & 127;
        whhT[k * G_ + g] = Whh[i];
    }
    for (int i = id; i < FC1_ * H_; i += np) {         // W_fc1 [256][128] -> [128][256]
        int o = i >> 7, k = i & 127;
        wfc1T[k * FC1_ + o] = Wfc1[i];
    }
    for (int i = id; i < O_ * FC1_; i += np) {         // W_fc2 [1024][256] -> [256][1024]
        int o = i >> 8, k = i & 255;
        wfc2T[k * O_ + o] = Wfc2[i];
    }
}

// ---------------- embedding: xs[b][t][e] ----------------
// xs[:,0,:] = init_emb ; xs[:,t,:] = message[:,t-1,:] @ W_emb^T + b_emb
__global__ void __launch_bounds__(256) embed_kernel(
    const float* __restrict__ msg, const float* __restrict__ W_emb,
    const float* __restrict__ b_emb, const float* __restrict__ init_emb,
    float* __restrict__ xs) {
    __shared__ float wlds[32 * 516];   // [e][v] padded row stride 516 (16B-aligned rows)
    for (int i = threadIdx.x; i < 32 * 512; i += 256) {
        int e = i >> 9, v = i & 511;
        wlds[e * 516 + v] = W_emb[i];
    }
    __syncthreads();
    const int e = threadIdx.x & 31;
    const int grp  = blockIdx.x * 8 + (threadIdx.x >> 5);
    const int ngrp = gridDim.x * 8;
    const float be = b_emb[e];
    const float ie = init_emb[e];
    const float* wr = wlds + e * 516;
    for (int task = grp; task < B_ * T_; task += ngrp) {
        float* dst = xs + (size_t)task * E_ + e;
        if ((task & 63) == 0) { *dst = ie; continue; }   // t==0 row
        const float* row = msg + (size_t)(task - 1) * V_;
        float a0 = 0.f, a1 = 0.f, a2 = 0.f, a3 = 0.f;
        #pragma unroll 8
        for (int v = 0; v < 512; v += 16) {
            float4 m0 = *(const float4*)(row + v);
            float4 m1 = *(const float4*)(row + v + 4);
            float4 m2 = *(const float4*)(row + v + 8);
            float4 m3 = *(const float4*)(row + v + 12);
            float4 w0 = *(const float4*)(wr + v);
            float4 w1 = *(const float4*)(wr + v + 4);
            float4 w2 = *(const float4*)(wr + v + 8);
            float4 w3 = *(const float4*)(wr + v + 12);
            a0 += m0.x * w0.x + m0.y * w0.y + m0.z * w0.z + m0.w * w0.w;
            a1 += m1.x * w1.x + m1.y * w1.y + m1.z * w1.z + m1.w * w1.w;
            a2 += m2.x * w2.x + m2.y * w2.y + m2.z * w2.z + m2.w * w2.w;
            a3 += m3.x * w3.x + m3.y * w3.y + m3.z * w3.z + m3.w * w3.w;
        }
        *dst = a0 + a1 + a2 + a3 + be;
    }
}

// ---------------- persistent GRU + FC1 + FC2 ----------------
// block = 256 threads (4 waves), owns 16 batch rows. wave w -> rows 4w..4w+3.
// lane l (0..63) -> gate columns g = l + 64*j, j=0..5:
//   j 0,1 -> r-gate for hh = l, l+64 ; j 2,3 -> z ; j 4,5 -> n  (thread-local gate triplets)
__global__ void __launch_bounds__(256) gru_fc_kernel(
    const float* __restrict__ xs,
    const float* __restrict__ wihT, const float* __restrict__ whhT,
    const float* __restrict__ b_ih, const float* __restrict__ b_hh,
    const float* __restrict__ wfc1T, const float* __restrict__ b_fc1,
    const float* __restrict__ wfc2T, const float* __restrict__ b_fc2,
    float* __restrict__ out) {
    __shared__ float hsh[16][128];
    __shared__ float xsl[16][32];
    __shared__ float hid[16][256];
    const int tid = threadIdx.x;
    const int l = tid & 63;
    const int w = tid >> 6;
    const int b0 = blockIdx.x * 16;

    for (int i = tid; i < 16 * 128; i += 256) hsh[i >> 7][i & 127] = 0.0f;
    float bi6[6], bh6[6];
    #pragma unroll
    for (int j = 0; j < 6; j++) { bi6[j] = b_ih[l + 64 * j]; bh6[j] = b_hh[l + 64 * j]; }
    __syncthreads();

    for (int t = 0; t < T_; t++) {
        for (int i = tid; i < 16 * 32; i += 256) {
            int r = i >> 5, e = i & 31;
            xsl[r][e] = xs[((size_t)(b0 + r) * T_ + t) * E_ + e];
        }
        __syncthreads();

        float ah[4][6], ai[4][6];
        #pragma unroll
        for (int r = 0; r < 4; r++)
            #pragma unroll
            for (int j = 0; j < 6; j++) { ah[r][j] = bh6[j]; ai[r][j] = bi6[j]; }

        // gh = h @ W_hh^T + b_hh   (K=128)
        #pragma unroll 2
        for (int k = 0; k < 128; k++) {
            float wv[6], hv[4];
            #pragma unroll
            for (int j = 0; j < 6; j++) wv[j] = whhT[k * G_ + l + 64 * j];
            #pragma unroll
            for (int r = 0; r < 4; r++) hv[r] = hsh[4 * w + r][k];
            #pragma unroll
            for (int r = 0; r < 4; r++)
                #pragma unroll
                for (int j = 0; j < 6; j++) ah[r][j] = fmaf(hv[r], wv[j], ah[r][j]);
        }
        // gi = x_t @ W_ih^T + b_ih   (K=32)
        #pragma unroll 2
        for (int e = 0; e < 32; e++) {
            float wv[6], xv[4];
            #pragma unroll
            for (int j = 0; j < 6; j++) wv[j] = wihT[e * G_ + l + 64 * j];
            #pragma unroll
            for (int r = 0; r < 4; r++) xv[r] = xsl[4 * w + r][e];
            #pragma unroll
            for (int r = 0; r < 4; r++)
                #pragma unroll
                for (int j = 0; j < 6; j++) ai[r][j] = fmaf(xv[r], wv[j], ai[r][j]);
        }
        __syncthreads();   // all gh reads of h done before we overwrite h

        #pragma unroll
        for (int r = 0; r < 4; r++) {
            int b = 4 * w + r;
            #pragma unroll
            for (int half = 0; half < 2; half++) {
                float rg = sigf(ai[r][half] + ah[r][half]);
                float zg = sigf(ai[r][2 + half] + ah[r][2 + half]);
                float ng = tanhfast(ai[r][4 + half] + rg * ah[r][4 + half]);
                int hh = l + 64 * half;
                float hold = hsh[b][hh];
                hsh[b][hh] = (1.0f - zg) * ng + zg * hold;
            }
        }
        // next iteration's top __syncthreads() orders these writes before gh reads
    }
    __syncthreads();

    // FC1: hid = elu(h @ W_fc1^T + b_fc1)   [16][256]
    {
        float a1[4][4];
        #pragma unroll
        for (int j = 0; j < 4; j++) {
            float bj = b_fc1[l + 64 * j];
            #pragma unroll
            for (int r = 0; r < 4; r++) a1[r][j] = bj;
        }
        #pragma unroll 2
        for (int k = 0; k < 128; k++) {
            float wv[4], hv[4];
            #pragma unroll
            for (int j = 0; j < 4; j++) wv[j] = wfc1T[k * FC1_ + l + 64 * j];
            #pragma unroll
            for (int r = 0; r < 4; r++) hv[r] = hsh[4 * w + r][k];
            #pragma unroll
            for (int r = 0; r < 4; r++)
                #pragma unroll
                for (int j = 0; j < 4; j++) a1[r][j] = fmaf(hv[r], wv[j], a1[r][j]);
        }
        #pragma unroll
        for (int r = 0; r < 4; r++)
            #pragma unroll
            for (int j = 0; j < 4; j++) hid[4 * w + r][l + 64 * j] = eluf(a1[r][j]);
    }
    __syncthreads();

    // FC2: out = sigmoid(hid @ W_fc2^T + b_fc2)   [16][1024]
    {
        float a2[4][16];
        #pragma unroll
        for (int j = 0; j < 16; j++) {
            float bj = b_fc2[l + 64 * j];
            #pragma unroll
            for (int r = 0; r < 4; r++) a2[r][j] = bj;
        }
        #pragma unroll 2
        for (int k = 0; k < 256; k++) {
            float hv[4];
            #pragma unroll
            for (int r = 0; r < 4; r++) hv[r] = hid[4 * w + r][k];
            #pragma unroll
            for (int j = 0; j < 16; j++) {
                float wv = wfc2T[k * O_ + l + 64 * j];
                #pragma unroll
                for (int r = 0; r < 4; r++) a2[r][j] = fmaf(hv[r], wv, a2[r][j]);
            }
        }
        #pragma unroll
        for (int r = 0; r < 4; r++) {
            size_t rowoff = (size_t)(b0 + 4 * w + r) * O_;
            #pragma unroll
            for (int j = 0; j < 16; j++) out[rowoff + l + 64 * j] = sigf(a2[r][j]);
        }
    }
}

extern "C" void kernel_launch(void* const* d_in, const int* in_sizes, int n_in,
                              void* d_out, int out_size, void* d_ws, size_t ws_size,
                              hipStream_t stream) {
    const float* message  = (const float*)d_in[0];
    const float* W_emb    = (const float*)d_in[1];
    const float* b_emb    = (const float*)d_in[2];
    const float* init_emb = (const float*)d_in[3];
    const float* W_ih     = (const float*)d_in[4];
    const float* W_hh     = (const float*)d_in[5];
    const float* b_ih     = (const float*)d_in[6];
    const float* b_hh     = (const float*)d_in[7];
    const float* W_fc1    = (const float*)d_in[8];
    const float* b_fc1    = (const float*)d_in[9];
    const float* W_fc2    = (const float*)d_in[10];
    const float* b_fc2    = (const float*)d_in[11];
    float* out = (float*)d_out;

    float* ws    = (float*)d_ws;
    float* xs    = ws;                                  // B*T*E = 8,388,608 f
    float* wihT  = xs + (size_t)B_ * T_ * E_;           // 12,288 f
    float* whhT  = wihT + (size_t)E_ * G_;              // 49,152 f
    float* wfc1T = whhT + (size_t)H_ * G_;              // 32,768 f
    float* wfc2T = wfc1T + (size_t)H_ * FC1_;           // 262,144 f
    // total ~35 MB of d_ws

    hipLaunchKernelGGL(prep_kernel, dim3(256), dim3(256), 0, stream,
                       W_ih, W_hh, W_fc1, W_fc2, wihT, whhT, wfc1T, wfc2T);
    hipLaunchKernelGGL(embed_kernel, dim3(2048), dim3(256), 0, stream,
                       message, W_emb, b_emb, init_emb, xs);
    hipLaunchKernelGGL(gru_fc_kernel, dim3(256), dim3(256), 0, stream,
                       xs, wihT, whhT, b_ih, b_hh, wfc1T, b_fc1, wfc2T, b_fc2, out);
}

// Round 2
// 219.305 us; speedup vs baseline: 8.3701x; 8.3701x over previous
//
#include <hip/hip_runtime.h>
#include <math.h>

#define B_ 4096
#define T_ 64
#define V_ 512
#define E_ 32
#define H_ 128
#define FC1_ 256
#define O_ 1024

typedef float f32x4 __attribute__((ext_vector_type(4)));
typedef short s16x8 __attribute__((ext_vector_type(8)));
typedef unsigned short u16;

#define MFMA16(a, b, c) __builtin_amdgcn_mfma_f32_16x16x32_bf16(a, b, c, 0, 0, 0)

union Frag { u16 q[8]; s16x8 v; };

__device__ __forceinline__ u16 f2bf(float f) {
    union { float f; unsigned u; } v; v.f = f;
    unsigned r = v.u + 0x7FFFu + ((v.u >> 16) & 1u);   // RNE
    return (u16)(r >> 16);
}
__device__ __forceinline__ float sigf(float x) { return 1.0f / (1.0f + __expf(-x)); }
__device__ __forceinline__ float tanhfast(float x) {
    return 1.0f - 2.0f / (__expf(2.0f * x) + 1.0f);
}

// ---------------- prep: pack all weights into MFMA B-fragment layout (bf16) ----
// B-frag for mfma_f32_16x16x32_bf16: lane l holds B[k0+(l>>4)*8+j][n0+(l&15)],
// with our B[k][n] = W[n][k] (we multiply h @ W^T). frag[l][j] = W[n0+(l&15)][k0+(l>>4)*8+j].
__global__ void __launch_bounds__(256) prep_kernel(
    const float* __restrict__ Wih, const float* __restrict__ Whh,
    const float* __restrict__ Wemb, const float* __restrict__ Wfc1,
    const float* __restrict__ Wfc2,
    u16* __restrict__ wihF, u16* __restrict__ whhF, u16* __restrict__ wembF,
    u16* __restrict__ wfc1F, u16* __restrict__ wfc2F) {
    int id = blockIdx.x * 256 + threadIdx.x;
    int np = gridDim.x * 256;
    // W_hh [384][128]: 24 gate tiles x 4 k-chunks
    for (int i = id; i < 24 * 4 * 64 * 8; i += np) {
        int j = i & 7, l = (i >> 3) & 63, kc = (i >> 9) & 3, gt = i >> 11;
        whhF[i] = f2bf(Whh[(gt * 16 + (l & 15)) * 128 + kc * 32 + (l >> 4) * 8 + j]);
    }
    // W_ih [384][32]: 24 gate tiles x 1 k-chunk
    for (int i = id; i < 24 * 64 * 8; i += np) {
        int j = i & 7, l = (i >> 3) & 63, gt = i >> 9;
        wihF[i] = f2bf(Wih[(gt * 16 + (l & 15)) * 32 + (l >> 4) * 8 + j]);
    }
    // W_emb [32][512]: 2 n-tiles x 16 k-chunks
    for (int i = id; i < 2 * 16 * 64 * 8; i += np) {
        int j = i & 7, l = (i >> 3) & 63, kc = (i >> 9) & 15, nt = i >> 13;
        wembF[i] = f2bf(Wemb[(nt * 16 + (l & 15)) * 512 + kc * 32 + (l >> 4) * 8 + j]);
    }
    // W_fc1 [256][128]: 16 o-tiles x 4 k-chunks
    for (int i = id; i < 16 * 4 * 64 * 8; i += np) {
        int j = i & 7, l = (i >> 3) & 63, kc = (i >> 9) & 3, ot = i >> 11;
        wfc1F[i] = f2bf(Wfc1[(ot * 16 + (l & 15)) * 128 + kc * 32 + (l >> 4) * 8 + j]);
    }
    // W_fc2 [1024][256]: 64 n-tiles x 8 k-chunks
    for (int i = id; i < 64 * 8 * 64 * 8; i += np) {
        int j = i & 7, l = (i >> 3) & 63, kc = (i >> 9) & 7, nt = i >> 12;
        wfc2F[i] = f2bf(Wfc2[(nt * 16 + (l & 15)) * 256 + kc * 32 + (l >> 4) * 8 + j]);
    }
}

// ---------------- embedding: xs A-frag packed --------------------------------
// tile = gb*64 + t (gb = batch-group of 16 rows). Output xs[tile][lane][8] bf16:
// A-frag layout: lane l holds x[b0+(l&15)][(l>>4)*8+j].
// x[:,0,:] = init_emb; x[:,t,:] = msg[:,t-1,:] @ W_emb^T + b_emb.
__global__ void __launch_bounds__(256) embed_kernel(
    const float* __restrict__ msg, const u16* __restrict__ wembF,
    const float* __restrict__ b_emb, const float* __restrict__ init_emb,
    u16* __restrict__ xs) {
    __shared__ u16 xlds[4][16 * 40];
    const int w = threadIdx.x >> 6, l = threadIdx.x & 63;
    const int ln = l & 15, lh = l >> 4;
    const int tile = blockIdx.x * 4 + w;
    const int gb = tile >> 6, t = tile & 63;
    u16* outp = xs + ((size_t)tile * 64 + l) * 8;
    if (t == 0) {
        Frag fr;
        #pragma unroll
        for (int j = 0; j < 8; j++) fr.q[j] = f2bf(init_emb[lh * 8 + j]);
        *(s16x8*)outp = fr.v;
        return;
    }
    float be0 = b_emb[ln], be1 = b_emb[16 + ln];
    f32x4 acc0 = {be0, be0, be0, be0};
    f32x4 acc1 = {be1, be1, be1, be1};
    const float* arow = msg + (size_t)((gb * 16 + ln) * 64 + (t - 1)) * 512 + lh * 8;
    const s16x8* wf = (const s16x8*)wembF;
    #pragma unroll
    for (int kc = 0; kc < 16; kc++) {
        float4 m0 = *(const float4*)(arow + kc * 32);
        float4 m1 = *(const float4*)(arow + kc * 32 + 4);
        Frag fa;
        fa.q[0] = f2bf(m0.x); fa.q[1] = f2bf(m0.y); fa.q[2] = f2bf(m0.z); fa.q[3] = f2bf(m0.w);
        fa.q[4] = f2bf(m1.x); fa.q[5] = f2bf(m1.y); fa.q[6] = f2bf(m1.z); fa.q[7] = f2bf(m1.w);
        acc0 = MFMA16(fa.v, wf[kc * 64 + l], acc0);
        acc1 = MFMA16(fa.v, wf[(16 + kc) * 64 + l], acc1);
    }
    // D-layout (rows lh*4+i, col nt*16+ln) -> LDS -> A-frag layout
    u16* xl = &xlds[w][0];
    #pragma unroll
    for (int i = 0; i < 4; i++) {
        int r = lh * 4 + i;
        xl[r * 40 + ln]      = f2bf(acc0[i]);
        xl[r * 40 + 16 + ln] = f2bf(acc1[i]);
    }
    s16x8 af = *(const s16x8*)(xl + ln * 40 + lh * 8);   // row ln, e = lh*8..+7
    *(s16x8*)outp = af;
}

// ---------------- persistent GRU + FC1 + FC2 (MFMA) --------------------------
// 256 blocks x 256 threads; block owns 16 batch rows. Wave w owns h-cols
// {16w..16w+15} and {64+16w..64+16w+15} (p=0,1) -> gate tiles gt = w+4p+8g.
__global__ void __launch_bounds__(256, 1) gru_fc_kernel(
    const u16* __restrict__ xs, const u16* __restrict__ whhF8,
    const u16* __restrict__ wihF8,
    const float* __restrict__ b_ih, const float* __restrict__ b_hh,
    const u16* __restrict__ wfc1F8, const float* __restrict__ b_fc1,
    const u16* __restrict__ wfc2F8, const float* __restrict__ b_fc2,
    float* __restrict__ out) {
    __shared__ u16 hlds[2][16 * 136];   // [row][col] bf16, row stride 136 (272B, 16B-aligned)
    __shared__ u16 hidl[16 * 264];      // FC1 out, row stride 264 (528B)
    const int tid = threadIdx.x, w = tid >> 6, l = tid & 63;
    const int ln = l & 15, lh = l >> 4;
    const int gb = blockIdx.x;

    for (int i = tid; i < 2 * 16 * 136; i += 256) ((u16*)hlds)[i] = 0;

    const s16x8* whhFv = (const s16x8*)whhF8;
    const s16x8* wihFv = (const s16x8*)wihF8;
    s16x8 wh[2][3][4], wi[2][3];
    float br[2], bz[2], bin[2], bgn[2];
    #pragma unroll
    for (int p = 0; p < 2; p++) {
        #pragma unroll
        for (int g = 0; g < 3; g++) {
            int gt = w + 4 * p + 8 * g;
            #pragma unroll
            for (int kc = 0; kc < 4; kc++) wh[p][g][kc] = whhFv[(gt * 4 + kc) * 64 + l];
            wi[p][g] = wihFv[gt * 64 + l];
        }
        int c = w * 16 + p * 64 + ln;
        br[p]  = b_ih[c] + b_hh[c];
        bz[p]  = b_ih[128 + c] + b_hh[128 + c];
        bin[p] = b_ih[256 + c];
        bgn[p] = b_hh[256 + c];
    }
    float hold[2][4] = {};
    const s16x8* xsf = ((const s16x8*)xs) + ((size_t)gb * 64 * 64 + l);
    s16x8 xcur = xsf[0];
    __syncthreads();

    const int aoff = ln * 136 + lh * 8;   // u16 units; + kc*32

    for (int t = 0; t < 64; t++) {
        s16x8 xnext = xsf[(t < 63 ? t + 1 : 63) * 64];
        const u16* hb = hlds[t & 1];
        s16x8 af0 = *(const s16x8*)(hb + aoff);
        s16x8 af1 = *(const s16x8*)(hb + aoff + 32);
        s16x8 af2 = *(const s16x8*)(hb + aoff + 64);
        s16x8 af3 = *(const s16x8*)(hb + aoff + 96);
        f32x4 ar[2], az[2], agn[2], ain[2];
        #pragma unroll
        for (int p = 0; p < 2; p++) {
            ar[p]  = {br[p], br[p], br[p], br[p]};
            az[p]  = {bz[p], bz[p], bz[p], bz[p]};
            agn[p] = {bgn[p], bgn[p], bgn[p], bgn[p]};
            ain[p] = {bin[p], bin[p], bin[p], bin[p]};
        }
        #pragma unroll
        for (int p = 0; p < 2; p++) {
            ar[p]  = MFMA16(af0, wh[p][0][0], ar[p]);
            ar[p]  = MFMA16(af1, wh[p][0][1], ar[p]);
            ar[p]  = MFMA16(af2, wh[p][0][2], ar[p]);
            ar[p]  = MFMA16(af3, wh[p][0][3], ar[p]);
            az[p]  = MFMA16(af0, wh[p][1][0], az[p]);
            az[p]  = MFMA16(af1, wh[p][1][1], az[p]);
            az[p]  = MFMA16(af2, wh[p][1][2], az[p]);
            az[p]  = MFMA16(af3, wh[p][1][3], az[p]);
            agn[p] = MFMA16(af0, wh[p][2][0], agn[p]);
            agn[p] = MFMA16(af1, wh[p][2][1], agn[p]);
            agn[p] = MFMA16(af2, wh[p][2][2], agn[p]);
            agn[p] = MFMA16(af3, wh[p][2][3], agn[p]);
            ar[p]  = MFMA16(xcur, wi[p][0], ar[p]);
            az[p]  = MFMA16(xcur, wi[p][1], az[p]);
            ain[p] = MFMA16(xcur, wi[p][2], ain[p]);
        }
        u16* hw = (u16*)hlds[(t + 1) & 1];
        #pragma unroll
        for (int p = 0; p < 2; p++) {
            int colo = w * 16 + p * 64 + ln;
            #pragma unroll
            for (int i = 0; i < 4; i++) {
                float rg = sigf(ar[p][i]);
                float zg = sigf(az[p][i]);
                float ng = tanhfast(ain[p][i] + rg * agn[p][i]);
                float hn = zg * (hold[p][i] - ng) + ng;
                hold[p][i] = hn;
                hw[(lh * 4 + i) * 136 + colo] = f2bf(hn);
            }
        }
        __syncthreads();
        xcur = xnext;
    }

    // ---- FC1: hid = elu(h @ W_fc1^T + b_fc1), [16][256] ----
    const u16* hb = hlds[0];   // final h written to buffer (63+1)&1 = 0
    s16x8 hf0 = *(const s16x8*)(hb + aoff);
    s16x8 hf1 = *(const s16x8*)(hb + aoff + 32);
    s16x8 hf2 = *(const s16x8*)(hb + aoff + 64);
    s16x8 hf3 = *(const s16x8*)(hb + aoff + 96);
    const s16x8* w1v = (const s16x8*)wfc1F8;
    #pragma unroll
    for (int q = 0; q < 4; q++) {
        int ot = w * 4 + q;
        float b1 = b_fc1[ot * 16 + ln];
        f32x4 a1 = {b1, b1, b1, b1};
        a1 = MFMA16(hf0, w1v[(ot * 4 + 0) * 64 + l], a1);
        a1 = MFMA16(hf1, w1v[(ot * 4 + 1) * 64 + l], a1);
        a1 = MFMA16(hf2, w1v[(ot * 4 + 2) * 64 + l], a1);
        a1 = MFMA16(hf3, w1v[(ot * 4 + 3) * 64 + l], a1);
        #pragma unroll
        for (int i = 0; i < 4; i++) {
            float v = a1[i];
            v = v > 0.0f ? v : (__expf(v) - 1.0f);
            hidl[(lh * 4 + i) * 264 + ot * 16 + ln] = f2bf(v);
        }
    }
    __syncthreads();

    // ---- FC2: out = sigmoid(hid @ W_fc2^T + b_fc2), [16][1024] ----
    s16x8 hf[8];
    #pragma unroll
    for (int kc = 0; kc < 8; kc++)
        hf[kc] = *(const s16x8*)(hidl + ln * 264 + kc * 32 + lh * 8);
    const s16x8* w2v = (const s16x8*)wfc2F8;
    #pragma unroll
    for (int q = 0; q < 16; q++) {
        int nt = w * 16 + q;
        float b2 = b_fc2[nt * 16 + ln];
        f32x4 a2 = {b2, b2, b2, b2};
        #pragma unroll
        for (int kc = 0; kc < 8; kc++)
            a2 = MFMA16(hf[kc], w2v[(nt * 8 + kc) * 64 + l], a2);
        #pragma unroll
        for (int i = 0; i < 4; i++)
            out[(size_t)(gb * 16 + lh * 4 + i) * 1024 + nt * 16 + ln] = sigf(a2[i]);
    }
}

extern "C" void kernel_launch(void* const* d_in, const int* in_sizes, int n_in,
                              void* d_out, int out_size, void* d_ws, size_t ws_size,
                              hipStream_t stream) {
    const float* message  = (const float*)d_in[0];
    const float* W_emb    = (const float*)d_in[1];
    const float* b_emb    = (const float*)d_in[2];
    const float* init_emb = (const float*)d_in[3];
    const float* W_ih     = (const float*)d_in[4];
    const float* W_hh     = (const float*)d_in[5];
    const float* b_ih     = (const float*)d_in[6];
    const float* b_hh     = (const float*)d_in[7];
    const float* W_fc1    = (const float*)d_in[8];
    const float* b_fc1    = (const float*)d_in[9];
    const float* W_fc2    = (const float*)d_in[10];
    const float* b_fc2    = (const float*)d_in[11];
    float* out = (float*)d_out;

    u16* xs    = (u16*)d_ws;            // 256*64*64*8  = 16,777,216 u16 (A-frag packed x)
    u16* whhF  = xs    + 16777216;      // 24*4*64*8    = 49,152
    u16* wihF  = whhF  + 49152;         // 24*64*8      = 12,288
    u16* wembF = wihF  + 12288;         // 2*16*64*8    = 16,384
    u16* wfc1F = wembF + 16384;         // 16*4*64*8    = 32,768
    u16* wfc2F = wfc1F + 32768;         // 64*8*64*8    = 262,144   (total ~34.3 MB)

    hipLaunchKernelGGL(prep_kernel, dim3(256), dim3(256), 0, stream,
                       W_ih, W_hh, W_emb, W_fc1, W_fc2, wihF, whhF, wembF, wfc1F, wfc2F);
    hipLaunchKernelGGL(embed_kernel, dim3(4096), dim3(256), 0, stream,
                       message, wembF, b_emb, init_emb, xs);
    hipLaunchKernelGGL(gru_fc_kernel, dim3(256), dim3(256), 0, stream,
                       xs, whhF, wihF, b_ih, b_hh, wfc1F, b_fc1, wfc2F, b_fc2, out);
}

// Round 3
// 146.993 us; speedup vs baseline: 12.4877x; 1.4919x over previous
//
#include <hip/hip_runtime.h>
#include <math.h>

#define B_ 4096
#define T_ 64
#define V_ 512
#define E_ 32
#define H_ 128
#define FC1_ 256
#define O_ 1024

typedef float f32x4 __attribute__((ext_vector_type(4)));
typedef short s16x8 __attribute__((ext_vector_type(8)));
typedef unsigned short u16;

#define MFMA16(a, b, c) __builtin_amdgcn_mfma_f32_16x16x32_bf16(a, b, c, 0, 0, 0)

union Frag { u16 q[8]; s16x8 v; };

__device__ __forceinline__ u16 f2bf(float f) {
    union { float f; unsigned u; } v; v.f = f;
    unsigned r = v.u + 0x7FFFu + ((v.u >> 16) & 1u);   // RNE
    return (u16)(r >> 16);
}
__device__ __forceinline__ float sigf(float x) { return 1.0f / (1.0f + __expf(-x)); }
__device__ __forceinline__ float tanhfast(float x) {
    return 1.0f - 2.0f / (__expf(2.0f * x) + 1.0f);
}

// ---------------- prep: pack all weights into MFMA B-fragment layout (bf16) ----
// B-frag for mfma_f32_16x16x32_bf16: lane l holds B[k0+(l>>4)*8+j][n0+(l&15)],
// B[k][n] = W[n][k]. frag[l][j] = W[n0+(l&15)][k0+(l>>4)*8+j].
__global__ void __launch_bounds__(256) prep_kernel(
    const float* __restrict__ Wih, const float* __restrict__ Whh,
    const float* __restrict__ Wemb, const float* __restrict__ Wfc1,
    const float* __restrict__ Wfc2,
    u16* __restrict__ wihF, u16* __restrict__ whhF, u16* __restrict__ wembF,
    u16* __restrict__ wfc1F, u16* __restrict__ wfc2F) {
    int id = blockIdx.x * 256 + threadIdx.x;
    int np = gridDim.x * 256;
    for (int i = id; i < 24 * 4 * 64 * 8; i += np) {       // W_hh [384][128]
        int j = i & 7, l = (i >> 3) & 63, kc = (i >> 9) & 3, gt = i >> 11;
        whhF[i] = f2bf(Whh[(gt * 16 + (l & 15)) * 128 + kc * 32 + (l >> 4) * 8 + j]);
    }
    for (int i = id; i < 24 * 64 * 8; i += np) {           // W_ih [384][32]
        int j = i & 7, l = (i >> 3) & 63, gt = i >> 9;
        wihF[i] = f2bf(Wih[(gt * 16 + (l & 15)) * 32 + (l >> 4) * 8 + j]);
    }
    for (int i = id; i < 2 * 16 * 64 * 8; i += np) {       // W_emb [32][512]
        int j = i & 7, l = (i >> 3) & 63, kc = (i >> 9) & 15, nt = i >> 13;
        wembF[i] = f2bf(Wemb[(nt * 16 + (l & 15)) * 512 + kc * 32 + (l >> 4) * 8 + j]);
    }
    for (int i = id; i < 16 * 4 * 64 * 8; i += np) {       // W_fc1 [256][128]
        int j = i & 7, l = (i >> 3) & 63, kc = (i >> 9) & 3, ot = i >> 11;
        wfc1F[i] = f2bf(Wfc1[(ot * 16 + (l & 15)) * 128 + kc * 32 + (l >> 4) * 8 + j]);
    }
    for (int i = id; i < 64 * 8 * 64 * 8; i += np) {       // W_fc2 [1024][256]
        int j = i & 7, l = (i >> 3) & 63, kc = (i >> 9) & 7, nt = i >> 12;
        wfc2F[i] = f2bf(Wfc2[(nt * 16 + (l & 15)) * 256 + kc * 32 + (l >> 4) * 8 + j]);
    }
}

// ---------------- fused embed + GRU + FC1 + FC2 -------------------------------
// 256 blocks x 256 threads; block owns 16 batch rows (gb). Wave w owns h-cols
// {16w..16w+15} and {64+16w..+15} (p=0,1) -> gate tiles gt = w+4p+8g.
// Embedding of msg[:,t] computed during GRU step t (for x_{t+1}); wave w does
// k-chunks 4w..4w+3, partials reduced in LDS. Msg loads double-buffered 1 step
// ahead in registers.
__global__ void __launch_bounds__(256, 1) fused_kernel(
    const float* __restrict__ msg,
    const u16* __restrict__ whhF8, const u16* __restrict__ wihF8,
    const u16* __restrict__ wembF8,
    const float* __restrict__ b_ih, const float* __restrict__ b_hh,
    const float* __restrict__ b_emb, const float* __restrict__ init_emb,
    const u16* __restrict__ wfc1F8, const float* __restrict__ b_fc1,
    const u16* __restrict__ wfc2F8, const float* __restrict__ b_fc2,
    float* __restrict__ out) {
    __shared__ u16 hlds[2][16 * 136];    // h double buffer, row stride 136
    __shared__ float epart[4][512];      // embed partial sums per wave
    __shared__ u16 xfrag[16 * 40];       // x_{t+1} bf16, row stride 40
    __shared__ u16 hidl[16 * 264];       // FC1 out
    const int tid = threadIdx.x, w = tid >> 6, l = tid & 63;
    const int ln = l & 15, lh = l >> 4;
    const int gb = blockIdx.x;

    for (int i = tid; i < 16 * 136; i += 256) hlds[0][i] = 0;

    // ---- resident weight fragments ----
    const s16x8* whhFv = (const s16x8*)whhF8;
    const s16x8* wihFv = (const s16x8*)wihF8;
    const s16x8* wembFv = (const s16x8*)wembF8;
    s16x8 wh[2][3][4], wi[2][3], we0[4], we1[4];
    float br[2], bz[2], bin[2], bgn[2];
    #pragma unroll
    for (int p = 0; p < 2; p++) {
        #pragma unroll
        for (int g = 0; g < 3; g++) {
            int gt = w + 4 * p + 8 * g;
            #pragma unroll
            for (int kc = 0; kc < 4; kc++) wh[p][g][kc] = whhFv[(gt * 4 + kc) * 64 + l];
            wi[p][g] = wihFv[gt * 64 + l];
        }
        int c = w * 16 + p * 64 + ln;
        br[p]  = b_ih[c] + b_hh[c];
        bz[p]  = b_ih[128 + c] + b_hh[128 + c];
        bin[p] = b_ih[256 + c];
        bgn[p] = b_hh[256 + c];
    }
    #pragma unroll
    for (int kc = 0; kc < 4; kc++) {
        we0[kc] = wembFv[(4 * w + kc) * 64 + l];            // nt=0
        we1[kc] = wembFv[(16 + 4 * w + kc) * 64 + l];       // nt=1
    }
    const float bev = b_emb[tid & 31];

    // x_0 = init_emb broadcast (A-frag: lane l holds x[*][lh*8+j])
    s16x8 xcur;
    {
        Frag xi;
        #pragma unroll
        for (int j = 0; j < 8; j++) xi.q[j] = f2bf(init_emb[lh * 8 + j]);
        xcur = xi.v;
    }
    float hold[2][4] = {};
    // msg base for this lane: row (gb*16+ln), k-offset (4w)*32 + lh*8
    const float* mrow = msg + ((size_t)(gb * 16 + ln) * 64) * 512 + (4 * w) * 32 + lh * 8;
    f32x4 mA[8], mB[8];
    #pragma unroll
    for (int kc = 0; kc < 4; kc++) {                        // preload msg col 0
        mA[2 * kc]     = *(const f32x4*)(mrow + kc * 32);
        mA[2 * kc + 1] = *(const f32x4*)(mrow + kc * 32 + 4);
    }
    __syncthreads();

    const int aoff = ln * 136 + lh * 8;

#define GRU_STEP(T, MC, MN) do {                                               \
    const int t = (T);                                                         \
    const u16* hb = hlds[t & 1];                                               \
    s16x8 af0 = *(const s16x8*)(hb + aoff);                                    \
    s16x8 af1 = *(const s16x8*)(hb + aoff + 32);                               \
    s16x8 af2 = *(const s16x8*)(hb + aoff + 64);                               \
    s16x8 af3 = *(const s16x8*)(hb + aoff + 96);                               \
    if (t < 62) {                                                              \
        const float* p_ = mrow + (size_t)(t + 1) * 512;                        \
        _Pragma("unroll")                                                      \
        for (int kc = 0; kc < 4; kc++) {                                       \
            MN[2 * kc]     = *(const f32x4*)(p_ + kc * 32);                    \
            MN[2 * kc + 1] = *(const f32x4*)(p_ + kc * 32 + 4);                \
        }                                                                      \
    }                                                                          \
    f32x4 ar[2], az[2], agn[2], ain[2];                                        \
    _Pragma("unroll")                                                          \
    for (int p = 0; p < 2; p++) {                                              \
        ar[p]  = {br[p], br[p], br[p], br[p]};                                 \
        az[p]  = {bz[p], bz[p], bz[p], bz[p]};                                 \
        agn[p] = {bgn[p], bgn[p], bgn[p], bgn[p]};                             \
        ain[p] = {bin[p], bin[p], bin[p], bin[p]};                             \
    }                                                                          \
    _Pragma("unroll")                                                          \
    for (int p = 0; p < 2; p++) {                                              \
        ar[p]  = MFMA16(af0, wh[p][0][0], ar[p]);                              \
        ar[p]  = MFMA16(af1, wh[p][0][1], ar[p]);                              \
        ar[p]  = MFMA16(af2, wh[p][0][2], ar[p]);                              \
        ar[p]  = MFMA16(af3, wh[p][0][3], ar[p]);                              \
        az[p]  = MFMA16(af0, wh[p][1][0], az[p]);                              \
        az[p]  = MFMA16(af1, wh[p][1][1], az[p]);                              \
        az[p]  = MFMA16(af2, wh[p][1][2], az[p]);                              \
        az[p]  = MFMA16(af3, wh[p][1][3], az[p]);                              \
        agn[p] = MFMA16(af0, wh[p][2][0], agn[p]);                             \
        agn[p] = MFMA16(af1, wh[p][2][1], agn[p]);                             \
        agn[p] = MFMA16(af2, wh[p][2][2], agn[p]);                             \
        agn[p] = MFMA16(af3, wh[p][2][3], agn[p]);                             \
        ar[p]  = MFMA16(xcur, wi[p][0], ar[p]);                                \
        az[p]  = MFMA16(xcur, wi[p][1], az[p]);                                \
        ain[p] = MFMA16(xcur, wi[p][2], ain[p]);                               \
    }                                                                          \
    u16* hw = hlds[(t + 1) & 1];                                               \
    _Pragma("unroll")                                                          \
    for (int p = 0; p < 2; p++) {                                              \
        int colo = w * 16 + p * 64 + ln;                                       \
        _Pragma("unroll")                                                      \
        for (int i = 0; i < 4; i++) {                                          \
            float rg = sigf(ar[p][i]);                                         \
            float zg = sigf(az[p][i]);                                         \
            float ng = tanhfast(ain[p][i] + rg * agn[p][i]);                   \
            float hn = zg * (hold[p][i] - ng) + ng;                            \
            hold[p][i] = hn;                                                   \
            hw[(lh * 4 + i) * 136 + colo] = f2bf(hn);                          \
        }                                                                      \
    }                                                                          \
    if (t < 63) {                                                              \
        f32x4 e0 = {0.f, 0.f, 0.f, 0.f}, e1 = {0.f, 0.f, 0.f, 0.f};            \
        _Pragma("unroll")                                                      \
        for (int kc = 0; kc < 4; kc++) {                                       \
            Frag fa;                                                           \
            _Pragma("unroll")                                                  \
            for (int j = 0; j < 4; j++) {                                      \
                fa.q[j]     = f2bf(MC[2 * kc][j]);                             \
                fa.q[4 + j] = f2bf(MC[2 * kc + 1][j]);                         \
            }                                                                  \
            e0 = MFMA16(fa.v, we0[kc], e0);                                    \
            e1 = MFMA16(fa.v, we1[kc], e1);                                    \
        }                                                                      \
        _Pragma("unroll")                                                      \
        for (int i = 0; i < 4; i++) {                                          \
            epart[w][(lh * 4 + i) * 32 + ln]      = e0[i];                     \
            epart[w][(lh * 4 + i) * 32 + 16 + ln] = e1[i];                     \
        }                                                                      \
    }                                                                          \
    __syncthreads();                                                           \
    if (t < 63) {                                                              \
        _Pragma("unroll")                                                      \
        for (int u = 0; u < 2; u++) {                                          \
            int f = tid + 256 * u;                                             \
            float s = epart[0][f] + epart[1][f] + epart[2][f] + epart[3][f]    \
                      + bev;                                                   \
            xfrag[(f >> 5) * 40 + (f & 31)] = f2bf(s);                         \
        }                                                                      \
        __syncthreads();                                                       \
        xcur = *(const s16x8*)(xfrag + ln * 40 + lh * 8);                      \
    }                                                                          \
} while (0)

    for (int tt = 0; tt < 64; tt += 2) {
        GRU_STEP(tt, mA, mB);
        GRU_STEP(tt + 1, mB, mA);
    }
#undef GRU_STEP

    // ---- FC1: hid = elu(h @ W_fc1^T + b_fc1), [16][256] ----
    const u16* hb = hlds[0];   // final h in buffer (63+1)&1 = 0
    s16x8 hf0 = *(const s16x8*)(hb + aoff);
    s16x8 hf1 = *(const s16x8*)(hb + aoff + 32);
    s16x8 hf2 = *(const s16x8*)(hb + aoff + 64);
    s16x8 hf3 = *(const s16x8*)(hb + aoff + 96);
    const s16x8* w1v = (const s16x8*)wfc1F8;
    #pragma unroll
    for (int q = 0; q < 4; q++) {
        int ot = w * 4 + q;
        float b1 = b_fc1[ot * 16 + ln];
        f32x4 a1 = {b1, b1, b1, b1};
        a1 = MFMA16(hf0, w1v[(ot * 4 + 0) * 64 + l], a1);
        a1 = MFMA16(hf1, w1v[(ot * 4 + 1) * 64 + l], a1);
        a1 = MFMA16(hf2, w1v[(ot * 4 + 2) * 64 + l], a1);
        a1 = MFMA16(hf3, w1v[(ot * 4 + 3) * 64 + l], a1);
        #pragma unroll
        for (int i = 0; i < 4; i++) {
            float v = a1[i];
            v = v > 0.0f ? v : (__expf(v) - 1.0f);
            hidl[(lh * 4 + i) * 264 + ot * 16 + ln] = f2bf(v);
        }
    }
    __syncthreads();

    // ---- FC2: out = sigmoid(hid @ W_fc2^T + b_fc2), [16][1024] ----
    s16x8 hf[8];
    #pragma unroll
    for (int kc = 0; kc < 8; kc++)
        hf[kc] = *(const s16x8*)(hidl + ln * 264 + kc * 32 + lh * 8);
    const s16x8* w2v = (const s16x8*)wfc2F8;
    #pragma unroll
    for (int q = 0; q < 16; q++) {
        int nt = w * 16 + q;
        float b2 = b_fc2[nt * 16 + ln];
        f32x4 a2 = {b2, b2, b2, b2};
        #pragma unroll
        for (int kc = 0; kc < 8; kc++)
            a2 = MFMA16(hf[kc], w2v[(nt * 8 + kc) * 64 + l], a2);
        #pragma unroll
        for (int i = 0; i < 4; i++)
            out[(size_t)(gb * 16 + lh * 4 + i) * 1024 + nt * 16 + ln] = sigf(a2[i]);
    }
}

extern "C" void kernel_launch(void* const* d_in, const int* in_sizes, int n_in,
                              void* d_out, int out_size, void* d_ws, size_t ws_size,
                              hipStream_t stream) {
    const float* message  = (const float*)d_in[0];
    const float* W_emb    = (const float*)d_in[1];
    const float* b_emb    = (const float*)d_in[2];
    const float* init_emb = (const float*)d_in[3];
    const float* W_ih     = (const float*)d_in[4];
    const float* W_hh     = (const float*)d_in[5];
    const float* b_ih     = (const float*)d_in[6];
    const float* b_hh     = (const float*)d_in[7];
    const float* W_fc1    = (const float*)d_in[8];
    const float* b_fc1    = (const float*)d_in[9];
    const float* W_fc2    = (const float*)d_in[10];
    const float* b_fc2    = (const float*)d_in[11];
    float* out = (float*)d_out;

    u16* whhF  = (u16*)d_ws;            // 24*4*64*8 = 49,152
    u16* wihF  = whhF  + 49152;         // 24*64*8   = 12,288
    u16* wembF = wihF  + 12288;         // 2*16*64*8 = 16,384
    u16* wfc1F = wembF + 16384;         // 16*4*64*8 = 32,768
    u16* wfc2F = wfc1F + 32768;         // 64*8*64*8 = 262,144  (total ~0.75 MB)

    hipLaunchKernelGGL(prep_kernel, dim3(256), dim3(256), 0, stream,
                       W_ih, W_hh, W_emb, W_fc1, W_fc2, wihF, whhF, wembF, wfc1F, wfc2F);
    hipLaunchKernelGGL(fused_kernel, dim3(256), dim3(256), 0, stream,
                       message, whhF, wihF, wembF, b_ih, b_hh, b_emb, init_emb,
                       wfc1F, b_fc1, wfc2F, b_fc2, out);
}